// Round 2
// baseline (313.274 us; speedup 1.0000x reference)
//
#include <hip/hip_runtime.h>
#include <math.h>

// ---------------------------------------------------------------------------
// InterLevelAttention, MI355X. Fixed shapes from setup_inputs().
// Round 7: barrier-free wave-level register GEMM (no LDS at all). Each wave
// owns a 64x64 tile; A/B fragments loaded straight from global into MFMA
// layout, fp32 A packed to bf16 in-register. A depth-3 / B depth-2 register
// pipeline; MT=2 M-tile loop amortizes fill; r_kernel fused into o_kernel;
// Xt consumed fp32 directly (cast kernel now weights-only).
// ---------------------------------------------------------------------------
constexpr int B_    = 4;
constexpr int HT    = 64,  WT = 64;
constexpr int HB    = 128, WB = 128;
constexpr int DIM   = 256;
constexpr int KVD   = 512;
constexpr int HEADS = 8;
constexpr int NP2   = 16;
constexpr int NPIX  = HB * WB;       // 16384
constexpr int NWIN  = HT * WT;       // 4096
constexpr float SCALE = 0.17677669529663687f;  // 32^-0.5

using bf16x8 = __attribute__((ext_vector_type(8))) short;
using f32x4  = __attribute__((ext_vector_type(4))) float;

__device__ __forceinline__ unsigned short f2bf(float f) {
  union { float f; unsigned u; } v; v.f = f;
  unsigned r = v.u + 0x7fffu + ((v.u >> 16) & 1u);   // RNE
  return (unsigned short)(r >> 16);
}
// pack 2 fp32 -> 2 bf16 in one dword: round-half-away (+0x8000) + v_perm.
__device__ __forceinline__ unsigned pack_bf16(float x, float y) {
  unsigned ux = __float_as_uint(x) + 0x8000u;
  unsigned uy = __float_as_uint(y) + 0x8000u;
  return __builtin_amdgcn_perm(uy, ux, 0x07060302u);  // lo=hi16(ux), hi=hi16(uy)
}
__device__ __forceinline__ bf16x8 pack8(const float4 x, const float4 y) {
  union { unsigned u[4]; bf16x8 v; } r;
  r.u[0] = pack_bf16(x.x, x.y);
  r.u[1] = pack_bf16(x.z, x.w);
  r.u[2] = pack_bf16(y.x, y.y);
  r.u[3] = pack_bf16(y.z, y.w);
  return r.v;
}

// ---------------------------------------------------------------------------
// Weight cast only (Xt/Xb consumed fp32 by the GEMMs now).
// ---------------------------------------------------------------------------
constexpr int NQW4  = DIM * DIM / 4;         // 16,384
constexpr int NKVW4 = KVD * KVD / 4;         // 65,536
constexpr int NCW4  = NQW4 + NKVW4 + NQW4;   // 98,304 -> 384 blocks

__global__ __launch_bounds__(256) void cast_w(
    const float* __restrict__ qw, const float* __restrict__ kvw,
    const float* __restrict__ pw,
    unsigned short* __restrict__ qwh, unsigned short* __restrict__ kvwh,
    unsigned short* __restrict__ pwh)
{
  const int i = blockIdx.x * 256 + threadIdx.x;
  const float* src; unsigned short* dst; int off;
  if (i < NQW4)              { src = qw;  dst = qwh;  off = i; }
  else if (i < NQW4 + NKVW4) { src = kvw; dst = kvwh; off = i - NQW4; }
  else                       { src = pw;  dst = pwh;  off = i - NQW4 - NKVW4; }
  float4 v = ((const float4*)src)[off];
  ushort4 o;
  o.x = f2bf(v.x); o.y = f2bf(v.y); o.z = f2bf(v.z); o.w = f2bf(v.w);
  ((ushort4*)dst)[off] = o;
}

// ---------------------------------------------------------------------------
// Wave-level register GEMM: one wave computes a 64x64 tile of
// C[M,N] = A[M,K] @ Bw[N,K]^T (+bias). No LDS, no barriers.
// AD = A register-pipeline depth (3 for HBM fp32 streams, 2 for L3-hot bf16).
// MT = M-tiles (128 rows apart) processed back-to-back, pipeline stays hot.
// ---------------------------------------------------------------------------
template<bool AF32, int AD, int KC, int NC, int MT, bool BF16_OUT, bool BIAS>
__device__ __forceinline__ void rgemm(
    const void* __restrict__ Ap, const unsigned short* __restrict__ Bw,
    const float* __restrict__ bias, void* __restrict__ Cp,
    const int m0, const int n0)
{
  constexpr int KS = KC / 32;       // K-steps per tile
  constexpr int U  = MT * KS;       // total steps
  const int lane = threadIdx.x & 63;
  const int fr = lane & 15;
  const int fk = (lane >> 4) * 8;

  const unsigned short* __restrict__ Ab = (const unsigned short*)Ap;
  const float* __restrict__          Af = (const float*)Ap;

  f32x4 acc[4][4];
#pragma unroll
  for (int i = 0; i < 4; ++i)
#pragma unroll
    for (int j = 0; j < 4; ++j) { f32x4 z = {0.f,0.f,0.f,0.f}; acc[i][j] = z; }

  bf16x8 a16[AF32 ? 1 : AD][4];
  float4 a32[AF32 ? AD : 1][4][2];
  bf16x8 b16[2][4];

  auto loadA = [&](int u, int buf) {
    const int ar = m0 + (u / KS) * 128;
    const int ko = (u % KS) * 32 + fk;
#pragma unroll
    for (int t = 0; t < 4; ++t) {
      const size_t ao = (size_t)(ar + t * 16 + fr) * KC + ko;
      if constexpr (AF32) {
        a32[buf][t][0] = *(const float4*)(Af + ao);
        a32[buf][t][1] = *(const float4*)(Af + ao + 4);
      } else {
        a16[buf][t] = *(const bf16x8*)(Ab + ao);
      }
    }
  };
  auto loadB = [&](int u, int buf) {
    const int ko = (u % KS) * 32 + fk;
#pragma unroll
    for (int t = 0; t < 4; ++t)
      b16[buf][t] = *(const bf16x8*)(Bw + (size_t)(n0 + t * 16 + fr) * KC + ko);
  };

#pragma unroll
  for (int d = 0; d < AD; ++d) loadA(d, d);
  loadB(0, 0);
  loadB(1, 1);

#pragma unroll
  for (int u = 0; u < U; ++u) {
    const int ab = u % AD;     // compile-time after unroll (rule #20 safe)
    const int bb = u & 1;
    bf16x8 af[4];
#pragma unroll
    for (int t = 0; t < 4; ++t) {
      if constexpr (AF32) af[t] = pack8(a32[ab][t][0], a32[ab][t][1]);
      else                af[t] = a16[ab][t];
    }
    __builtin_amdgcn_s_setprio(1);
#pragma unroll
    for (int mt = 0; mt < 4; ++mt)
#pragma unroll
      for (int nt = 0; nt < 4; ++nt)
        acc[mt][nt] = __builtin_amdgcn_mfma_f32_16x16x32_bf16(
            af[mt], b16[bb][nt], acc[mt][nt], 0, 0, 0);
    __builtin_amdgcn_s_setprio(0);
    if (u + AD < U) loadA(u + AD, ab);   // WAR on frags orders after MFMAs
    if (u + 2  < U) loadB(u + 2, bb);

    if (((u + 1) % KS) == 0) {           // tile finished: store + re-zero
      const int mb = m0 + (u / KS) * 128;
      const int col0 = lane & 15, rb = (lane >> 4) * 4;
#pragma unroll
      for (int mt = 0; mt < 4; ++mt)
#pragma unroll
        for (int nt = 0; nt < 4; ++nt) {
          const int col = n0 + nt * 16 + col0;
          const float bv = BIAS ? bias[col] : 0.f;
#pragma unroll
          for (int r = 0; r < 4; ++r) {
            const int row = mb + mt * 16 + rb + r;
            const float v = acc[mt][nt][r] + bv;
            if constexpr (BF16_OUT)
              ((unsigned short*)Cp)[(size_t)row * NC + col] = f2bf(v);
            else
              ((float*)Cp)[(size_t)row * NC + col] = v;
          }
          if constexpr (MT > 1) { f32x4 z = {0.f,0.f,0.f,0.f}; acc[mt][nt] = z; }
        }
    }
  }
}

// ---------------------------------------------------------------------------
// Merged GEMM1 (Q proj, fp32 A) + GEMM2 (KV proj, fp32 A, direct from Xt).
// Runs of 8 consecutive block ids alternate kinds -> every XCD hosts both.
// G1: M=65536 N=256 K=256, block=256x128 (MT=2), 512 blocks.
// G2: M=16384 N=512 K=512, block=128x128 (MT=1), 512 blocks.
// ---------------------------------------------------------------------------
__global__ __launch_bounds__(256, 2) void g12_kernel(
    const float* __restrict__ Xb, const unsigned short* __restrict__ qwh,
    unsigned short* __restrict__ Qh,
    const float* __restrict__ Xt, const unsigned short* __restrict__ kvwh,
    unsigned short* __restrict__ KVh)
{
  const int wave = threadIdx.x >> 6;
  const int wr = wave >> 1, wc = wave & 1;
  const int id = blockIdx.x;
  const int g = id >> 3, r = id & 7;
  const int i = (g >> 1) * 8 + r;          // linear index within kind
  if ((g & 1) == 0) {
    const int bx = i >> 1, by = i & 1;
    rgemm<true, 3, 256, 256, 2, true, false>(
        Xb, qwh, nullptr, Qh, bx * 256 + wr * 64, by * 128 + wc * 64);
  } else {
    const int bx = i >> 2, by = i & 3;
    rgemm<true, 3, 512, 512, 1, true, false>(
        Xt, kvwh, nullptr, KVh, bx * 128 + wr * 64, by * 128 + wc * 64);
  }
}

// GEMM3: out proj, bf16 A (L3-hot Oh), fp32 out + bias. 512 blocks, MT=2.
__global__ __launch_bounds__(256) void g3_kernel(
    const unsigned short* __restrict__ Oh, const unsigned short* __restrict__ pwh,
    const float* __restrict__ pb, float* __restrict__ out)
{
  const int wave = threadIdx.x >> 6;
  const int wr = wave >> 1, wc = wave & 1;
  const int id = blockIdx.x;
  const int bx = id >> 1, by = id & 1;
  rgemm<false, 2, 256, 256, 2, false, true>(
      Oh, pwh, pb, out, bx * 256 + wr * 64, by * 128 + wc * 64);
}

// ---------------------------------------------------------------------------
// Fused e+s: one thread per (b, pixel, h). q loaded once; E contributions for
// the <=4 covering windows + folded sum S emitted directly.
// ---------------------------------------------------------------------------
__global__ __launch_bounds__(256) void es_kernel(
    const unsigned short* __restrict__ Qh, const unsigned short* __restrict__ KVh,
    const float* __restrict__ rel_init, const float* __restrict__ rel_bias,
    float* __restrict__ E, float* __restrict__ S)
{
  const int idx = blockIdx.x * 256 + threadIdx.x;
  const int h = idx & 7;
  const int x = (idx >> 3) & 127;
  const int y = (idx >> 10) & 127;
  const int b = idx >> 17;

  const uint4* qp = (const uint4*)(Qh + ((size_t)((b << 14) + y * WB + x)) * DIM + h * 32);
  uint4 q0 = qp[0], q1 = qp[1], q2 = qp[2], q3 = qp[3];
  const unsigned qa[16] = {q0.x,q0.y,q0.z,q0.w, q1.x,q1.y,q1.z,q1.w,
                           q2.x,q2.y,q2.z,q2.w, q3.x,q3.y,q3.z,q3.w};

  const int ilo = max(0, (y - 1) >> 1), ihi = min(HT - 1, (y + 1) >> 1);
  const int jlo = max(0, (x - 1) >> 1), jhi = min(WT - 1, (x + 1) >> 1);

  float s = 0.f;
  for (int i = ilo; i <= ihi; ++i)
    for (int j = jlo; j <= jhi; ++j) {
      const int w = i * WT + j;
      const int p = (y + 1 - 2 * i) * 4 + (x + 1 - 2 * j);
      const uint4* kp = (const uint4*)(KVh + ((size_t)((b << 12) + w)) * KVD + h * 32);
      uint4 k0 = kp[0], k1 = kp[1], k2 = kp[2], k3 = kp[3];
      const unsigned ka[16] = {k0.x,k0.y,k0.z,k0.w, k1.x,k1.y,k1.z,k1.w,
                               k2.x,k2.y,k2.z,k2.w, k3.x,k3.y,k3.z,k3.w};
      float acc = 0.f;
#pragma unroll
      for (int q = 0; q < 16; ++q) {
        acc = fmaf(__uint_as_float(qa[q] << 16),
                   __uint_as_float(ka[q] << 16), acc);
        acc = fmaf(__uint_as_float(qa[q] & 0xffff0000u),
                   __uint_as_float(ka[q] & 0xffff0000u), acc);
      }
      const float e = expf(acc * SCALE + rel_init[p] + rel_bias[p]);
      E[((size_t)((b << 12) + w)) * 128 + h * NP2 + p] = e;
      s += e;
    }
  S[(size_t)((b * HEADS + h) << 14) + y * WB + x] = s;
}

// ---------------------------------------------------------------------------
// out_pre[b,pix,c] (bf16) = sum over covering windows of (E/S_scrambled) * v.
// r_kernel folded in: R computed inline (faithful to reference reshape quirk:
// h_eff = w>>9; w_eff = (w&511)*8 + h; padding divisor -> 1).
// 8 channels/thread, 32 threads/pixel, 8 pixels/block.
// ---------------------------------------------------------------------------
__global__ __launch_bounds__(256) void o_kernel(
    const float* __restrict__ E, const float* __restrict__ S,
    const unsigned short* __restrict__ KVh,
    unsigned short* __restrict__ out_pre)
{
  const int t  = threadIdx.x;
  const int pg = blockIdx.x * 8 + (t >> 5);
  const int b  = pg >> 14;
  const int yx = pg & 16383;
  const int y  = yx >> 7, x = yx & 127;
  const int c8 = t & 31;
  const int h  = c8 >> 2;

  const int ilo = max(0, (y - 1) >> 1), ihi = min(HT - 1, (y + 1) >> 1);
  const int jlo = max(0, (x - 1) >> 1), jhi = min(WT - 1, (x + 1) >> 1);

  float acc[8] = {};
  for (int i = ilo; i <= ihi; ++i)
    for (int j = jlo; j <= jhi; ++j) {
      const int w = i * WT + j;
      const int p = (y + 1 - 2 * i) * 4 + (x + 1 - 2 * j);
      // inline R = E / S_scrambled
      const float e = E[((size_t)((b << 12) + w)) * 128 + h * NP2 + p];
      const int h_eff = w >> 9;
      const int w_eff = ((w & 511) << 3) + h;
      const int i2 = w_eff >> 6, j2 = w_eff & 63;
      const int y2 = 2 * i2 + (p >> 2) - 1;
      const int x2 = 2 * j2 + (p & 3) - 1;
      float sd = 1.f;
      if ((unsigned)y2 < (unsigned)HB && (unsigned)x2 < (unsigned)WB)
        sd = S[(size_t)((b * HEADS + h_eff) * NPIX) + y2 * WB + x2];
      const float rr = e / sd;

      const uint4 v = *(const uint4*)(KVh + ((size_t)(b * NWIN + w)) * KVD + 256 + c8 * 8);
      const unsigned vv[4] = {v.x, v.y, v.z, v.w};
#pragma unroll
      for (int q = 0; q < 4; ++q) {
        acc[2*q]   = fmaf(rr, __uint_as_float(vv[q] << 16),         acc[2*q]);
        acc[2*q+1] = fmaf(rr, __uint_as_float(vv[q] & 0xffff0000u), acc[2*q+1]);
      }
    }

  uint4 ov;
  ov.x = (unsigned)f2bf(acc[0]) | ((unsigned)f2bf(acc[1]) << 16);
  ov.y = (unsigned)f2bf(acc[2]) | ((unsigned)f2bf(acc[3]) << 16);
  ov.z = (unsigned)f2bf(acc[4]) | ((unsigned)f2bf(acc[5]) << 16);
  ov.w = (unsigned)f2bf(acc[6]) | ((unsigned)f2bf(acc[7]) << 16);
  *(uint4*)(out_pre + (size_t)pg * DIM + c8 * 8) = ov;
}

// ---------------------------------------------------------------------------
extern "C" void kernel_launch(void* const* d_in, const int* in_sizes, int n_in,
                              void* d_out, int out_size, void* d_ws, size_t ws_size,
                              hipStream_t stream) {
  const float* Xt       = (const float*)d_in[0];
  const float* Xb       = (const float*)d_in[1];
  const float* q_w      = (const float*)d_in[2];
  const float* kv_w     = (const float*)d_in[3];
  const float* proj_w   = (const float*)d_in[4];
  const float* proj_b   = (const float*)d_in[5];
  const float* rel_init = (const float*)d_in[6];
  const float* rel_bias = (const float*)d_in[7];
  float* out = (float*)d_out;

  char* ws = (char*)d_ws;
  const size_t nXb = (size_t)B_ * NPIX * DIM;
  const size_t nXt = (size_t)B_ * NWIN * KVD;
  const size_t nQW = (size_t)DIM * DIM;
  const size_t nKVW = (size_t)KVD * KVD;
  unsigned short* Qh   = (unsigned short*)ws;  ws += nXb * 2;   // 32 MB (reused as Oh)
  unsigned short* KVh  = (unsigned short*)ws;  ws += nXt * 2;   // 16 MB
  float*          E    = (float*)ws;           ws += (size_t)B_ * NWIN * 128 * 4;   // 8 MB
  float*          S    = (float*)ws;           ws += (size_t)B_ * HEADS * NPIX * 4; // 2 MB
  unsigned short* qwh  = (unsigned short*)ws;  ws += nQW * 2;
  unsigned short* kvwh = (unsigned short*)ws;  ws += nKVW * 2;
  unsigned short* pwh  = (unsigned short*)ws;  ws += nQW * 2;
  unsigned short* Oh   = Qh;            // alias: Qh dead after es_kernel

  const dim3 blk(256);

  // 0) weight cast only
  cast_w<<<dim3(NCW4 / 256), blk, 0, stream>>>(
      q_w, kv_w, proj_w, qwh, kvwh, pwh);

  // 1+2) merged Q proj + KV proj (both fp32 A, register GEMM)
  g12_kernel<<<dim3(1024), blk, 0, stream>>>(Xb, qwh, Qh, Xt, kvwh, KVh);

  // 3) fused E + S
  es_kernel<<<dim3(B_ * NPIX * HEADS / 256), blk, 0, stream>>>(
      Qh, KVh, rel_init, rel_bias, E, S);

  // 4+5) Oh = fold((E/S) * v)   [bf16, into Qh buffer; r_kernel fused]
  o_kernel<<<dim3(B_ * NPIX / 8), blk, 0, stream>>>(E, S, KVh, Oh);

  // 6) out = Oh @ proj_w^T + proj_b
  g3_kernel<<<dim3(B_ * NPIX / 128), blk, 0, stream>>>(Oh, pwh, proj_b, out);
}

// Round 3
// 257.521 us; speedup vs baseline: 1.2165x; 1.2165x over previous
//
#include <hip/hip_runtime.h>
#include <math.h>

// ---------------------------------------------------------------------------
// InterLevelAttention, MI355X. Fixed shapes from setup_inputs().
// Round 8: revert to R6 pipelined-LDS GEMM core (proven 56.5us g12).
// g3 mirrors the G2 config (BN=128, depth-2 prefetch, 3-buf, 1024 blocks).
// r_kernel stays fused into o_kernel (verified in R7). 5 dispatches.
// ---------------------------------------------------------------------------
constexpr int B_    = 4;
constexpr int HT    = 64,  WT = 64;
constexpr int HB    = 128, WB = 128;
constexpr int DIM   = 256;
constexpr int KVD   = 512;
constexpr int HEADS = 8;
constexpr int NP2   = 16;
constexpr int NPIX  = HB * WB;       // 16384
constexpr int NWIN  = HT * WT;       // 4096
constexpr float SCALE = 0.17677669529663687f;  // 32^-0.5

using bf16x8 = __attribute__((ext_vector_type(8))) short;
using f32x4  = __attribute__((ext_vector_type(4))) float;

__device__ __forceinline__ unsigned short f2bf(float f) {
  union { float f; unsigned u; } v; v.f = f;
  unsigned r = v.u + 0x7fffu + ((v.u >> 16) & 1u);   // RNE
  return (unsigned short)(r >> 16);
}
// pack 2 fp32 -> 2 bf16 in one dword: round-half-away (+0x8000) + v_perm.
__device__ __forceinline__ unsigned pack_bf16(float x, float y) {
  unsigned ux = __float_as_uint(x) + 0x8000u;
  unsigned uy = __float_as_uint(y) + 0x8000u;
  return __builtin_amdgcn_perm(uy, ux, 0x07060302u);  // lo=hi16(ux), hi=hi16(uy)
}

__device__ __forceinline__ void wait_vm0() { asm volatile("s_waitcnt vmcnt(0)" ::: "memory"); }
__device__ __forceinline__ void wait_vm4() { asm volatile("s_waitcnt vmcnt(4)" ::: "memory"); }
__device__ __forceinline__ void wait_vm6() { asm volatile("s_waitcnt vmcnt(6)" ::: "memory"); }
__device__ __forceinline__ void wait_lgkm0() { asm volatile("s_waitcnt lgkmcnt(0)" ::: "memory"); }

// ---------------------------------------------------------------------------
// Merged fp32->bf16 cast: Xt + q_w + kv_w + proj_w in one launch.
// ---------------------------------------------------------------------------
constexpr int NXT4  = B_ * NWIN * KVD / 4;   // 2,097,152
constexpr int NQW4  = DIM * DIM / 4;         // 16,384
constexpr int NKVW4 = KVD * KVD / 4;         // 65,536
constexpr int NCAST4 = NXT4 + NQW4 + NKVW4 + NQW4;

__global__ __launch_bounds__(256) void cast_all(
    const float* __restrict__ Xt, const float* __restrict__ qw,
    const float* __restrict__ kvw, const float* __restrict__ pw,
    unsigned short* __restrict__ Xth, unsigned short* __restrict__ qwh,
    unsigned short* __restrict__ kvwh, unsigned short* __restrict__ pwh)
{
  const int i = blockIdx.x * 256 + threadIdx.x;
  const float* src; unsigned short* dst; int off;
  if (i < NXT4)                     { src = Xt;  dst = Xth;  off = i; }
  else if (i < NXT4 + NQW4)         { src = qw;  dst = qwh;  off = i - NXT4; }
  else if (i < NXT4 + NQW4 + NKVW4) { src = kvw; dst = kvwh; off = i - NXT4 - NQW4; }
  else                              { src = pw;  dst = pwh;  off = i - NXT4 - NQW4 - NKVW4; }
  float4 v = ((const float4*)src)[off];
  ushort4 o;
  o.x = f2bf(v.x); o.y = f2bf(v.y); o.z = f2bf(v.z); o.w = f2bf(v.w);
  ((ushort4*)dst)[off] = o;
}

// ---------------------------------------------------------------------------
// Templated MFMA GEMM core: C[M,N] = A[M,K] @ Bw[N,K]^T (+bias).
// BM=128, BK=32, BN in {128,256}. 256 thr = 4 waves (2x2).
// Pipelined: next K-tile staged at top of iter, drained with counted vmcnt
// at the bottom (raw s_barrier — no compiler vmcnt(0) drain).
// ---------------------------------------------------------------------------
template<bool AF32, int BN, bool BF16_OUT, bool BIAS>
__device__ __forceinline__ void gemm_core(
    const void* __restrict__ Ap, const unsigned short* __restrict__ Bw,
    const float* __restrict__ bias, void* __restrict__ Cp,
    int M, int N, int K, int bx, int by,
    unsigned short* Ash, unsigned short* Bsh)
{
  constexpr int NT = BN / 32;          // n-frags per wave
  constexpr int NB = BN / 64;          // B global_load_lds per thread per tile
  const int tid  = threadIdx.x;
  const int wave = tid >> 6;
  const int lane = tid & 63;
  const int m0 = bx * 128;
  const int n0 = by * BN;
  const int wm = (wave >> 1) * 64;
  const int wn = (wave & 1) * (BN / 2);

  f32x4 acc[4][NT];
#pragma unroll
  for (int i = 0; i < 4; ++i)
#pragma unroll
    for (int j = 0; j < NT; ++j) { f32x4 z = {0.f, 0.f, 0.f, 0.f}; acc[i][j] = z; }

  const int fr = lane & 15;
  const int fk = (lane >> 4) * 8;
  const int niter = K >> 5;

  auto stageB = [&](int kk, int buf) {
#pragma unroll
    for (int i = 0; i < NB; ++i) {
      const int c = i * 256 + wave * 64 + lane, row = c >> 2, ko = (c & 3) * 8;
      __builtin_amdgcn_global_load_lds(
          (const __attribute__((address_space(1))) unsigned int*)
              (Bw + (size_t)(n0 + row) * K + kk + ko),
          (__attribute__((address_space(3))) unsigned int*)
              ((char*)Bsh + buf * (BN * 64) + i * 4096 + wave * 1024),
          16, 0, 0);
    }
  };

  auto compute = [&](int bufA, int bufB) {
    bf16x8 af[4], bfr[NT];
    const unsigned short* Abase = Ash + bufA * 4096;
    const unsigned short* Bbase = Bsh + bufB * (BN * 32);
#pragma unroll
    for (int x = 0; x < 4; ++x)
      af[x] = *(const bf16x8*)&Abase[(wm + x * 16 + fr) * 32 + fk];
#pragma unroll
    for (int x = 0; x < NT; ++x)
      bfr[x] = *(const bf16x8*)&Bbase[(wn + x * 16 + fr) * 32 + fk];
#pragma unroll
    for (int mt = 0; mt < 4; ++mt)
#pragma unroll
      for (int nt = 0; nt < NT; ++nt)
        acc[mt][nt] = __builtin_amdgcn_mfma_f32_16x16x32_bf16(
            af[mt], bfr[nt], acc[mt][nt], 0, 0, 0);
  };

  if constexpr (AF32) {
    // G1: A fp32 -> reg prefetch -> pack -> ds_write. 2-buf A and B.
    const float* Af = (const float*)Ap;
    float4 areg[4];
    auto loadA = [&](int kk) {
#pragma unroll
      for (int u = 0; u < 4; ++u) {
        const int c = u * 256 + tid, row = c >> 3, kq = (c & 7) * 4;
        areg[u] = *(const float4*)(Af + (size_t)(m0 + row) * K + kk + kq);
      }
    };
    auto writeA = [&](int buf) {
#pragma unroll
      for (int u = 0; u < 4; ++u) {
        const int c = u * 256 + tid, row = c >> 3, kq = (c & 7) * 4;
        uint2 pk;
        pk.x = pack_bf16(areg[u].x, areg[u].y);
        pk.y = pack_bf16(areg[u].z, areg[u].w);
        *(uint2*)&Ash[buf * 4096 + row * 32 + kq] = pk;
      }
    };

    // prologue: tile0 staged, areg(1) in flight
    loadA(0);
    stageB(0, 0);
    writeA(0);          // compiler drains areg(0) here
    loadA(32);          // areg(1)
    wait_vm4();         // drain B(0); leave areg(1) in flight
    wait_lgkm0();
    __builtin_amdgcn_s_barrier();

    for (int t = 0; t < niter; ++t) {
      const int cur = t & 1;
      const int kk = t << 5;
      if (t + 1 < niter) stageB(kk + 32, cur ^ 1);   // B(t+1) flies under MFMAs
      compute(cur, cur);
      if (t + 1 < niter) {
        writeA(cur ^ 1);              // areg(t+1): had a full iteration of flight
        if (t + 2 < niter) {
          loadA(kk + 64);             // areg(t+2)
          wait_vm4();                 // drain B(t+1); leave areg(t+2)
        } else {
          wait_vm0();
        }
        wait_lgkm0();                 // ds_write visible before barrier
        __builtin_amdgcn_s_barrier();
      }
    }
  } else {
    // G2/G3: A bf16 via global_load_lds. Depth-2 prefetch, 3-buf LDS.
    auto stageA = [&](int kk, int buf) {
      const unsigned short* Ab = (const unsigned short*)Ap;
#pragma unroll
      for (int i = 0; i < 2; ++i) {
        const int c = i * 256 + wave * 64 + lane, row = c >> 2, ko = (c & 3) * 8;
        __builtin_amdgcn_global_load_lds(
            (const __attribute__((address_space(1))) unsigned int*)
                (Ab + (size_t)(m0 + row) * K + kk + ko),
            (__attribute__((address_space(3))) unsigned int*)
                ((char*)Ash + buf * 8192 + i * 4096 + wave * 1024),
            16, 0, 0);
      }
    };
    auto wait_batch = [&]() {      // leave one tile-batch (2+NB loads) in flight
      if constexpr (NB == 2) wait_vm4(); else wait_vm6();
    };

    // prologue: stage tiles 0 and 1; drain batch0 only
    stageA(0, 0);  stageB(0, 0);
    stageA(32, 1); stageB(32, 1);
    wait_batch();
    __builtin_amdgcn_s_barrier();

    int rd = 0, wr = 2;
    for (int t = 0; t < niter; ++t) {
      const int kk = t << 5;
      if (t + 2 < niter) { stageA(kk + 64, wr); stageB(kk + 64, wr); }
      compute(rd, rd);
      if (t + 1 < niter) {
        if (t + 2 < niter) wait_batch();   // drain batch(t+1); leave batch(t+2)
        else               wait_vm0();
        __builtin_amdgcn_s_barrier();
      }
      rd = (rd == 2) ? 0 : rd + 1;
      wr = (wr == 2) ? 0 : wr + 1;
    }
  }

  // epilogue: C/D layout col=lane&15, row=(lane>>4)*4+reg
  const int col0 = lane & 15;
  const int rb   = (lane >> 4) * 4;
#pragma unroll
  for (int mt = 0; mt < 4; ++mt)
#pragma unroll
    for (int nt = 0; nt < NT; ++nt) {
      const int col = n0 + wn + nt * 16 + col0;
      float bv = BIAS ? bias[col] : 0.f;
#pragma unroll
      for (int r = 0; r < 4; ++r) {
        const int row = m0 + wm + mt * 16 + rb + r;
        const float v = acc[mt][nt][r] + bv;
        if (BF16_OUT) ((unsigned short*)Cp)[(size_t)row * N + col] = f2bf(v);
        else          ((float*)Cp)[(size_t)row * N + col] = v;
      }
    }
}

// ---------------------------------------------------------------------------
// Merged GEMM1 (Q proj, fp32 A, 128x256) + GEMM2 (KV proj, bf16, 128x128).
// Even block ids -> G1 (512), odd -> G2 (512): each CU hosts both kinds.
// LDS: Ash 3-buf (24 KB), Bsh max(2x16 KB [G1], 3x8 KB [G2]) = 32 KB.
// ---------------------------------------------------------------------------
__global__ __launch_bounds__(256, 2) void g12_kernel(
    const float* __restrict__ Xb, const unsigned short* __restrict__ qwh,
    unsigned short* __restrict__ Qh,
    const unsigned short* __restrict__ Xth, const unsigned short* __restrict__ kvwh,
    unsigned short* __restrict__ KVh)
{
  __shared__ unsigned short Ash[3 * 128 * 32];   // 24 KB
  __shared__ unsigned short Bsh[2 * 256 * 32];   // 32 KB
  const int id = blockIdx.x;
  if ((id & 1) == 0) {
    gemm_core<true, 256, true, false>(Xb, qwh, nullptr, Qh,
        B_ * NPIX, DIM, DIM, id >> 1, 0, Ash, Bsh);
  } else {
    const int t = id >> 1;
    gemm_core<false, 128, true, false>(Xth, kvwh, nullptr, KVh,
        B_ * NWIN, KVD, KVD, t >> 2, t & 3, Ash, Bsh);
  }
}

// GEMM3: out proj, bf16 A, BN=128 (G2 config), fp32 out + bias. 1024 blocks.
__global__ __launch_bounds__(256, 2) void g3_kernel(
    const unsigned short* __restrict__ Oh, const unsigned short* __restrict__ pwh,
    const float* __restrict__ pb, float* __restrict__ out)
{
  __shared__ unsigned short Ash[3 * 128 * 32];   // 24 KB
  __shared__ unsigned short Bsh[3 * 128 * 32];   // 24 KB
  const int id = blockIdx.x;
  gemm_core<false, 128, false, true>(Oh, pwh, pb, out,
      B_ * NPIX, DIM, DIM, id >> 1, id & 1, Ash, Bsh);
}

// ---------------------------------------------------------------------------
// Fused e+s: one thread per (b, pixel, h). q loaded once; E contributions for
// the <=4 covering windows + folded sum S emitted directly.
// ---------------------------------------------------------------------------
__global__ __launch_bounds__(256) void es_kernel(
    const unsigned short* __restrict__ Qh, const unsigned short* __restrict__ KVh,
    const float* __restrict__ rel_init, const float* __restrict__ rel_bias,
    float* __restrict__ E, float* __restrict__ S)
{
  const int idx = blockIdx.x * 256 + threadIdx.x;
  const int h = idx & 7;
  const int x = (idx >> 3) & 127;
  const int y = (idx >> 10) & 127;
  const int b = idx >> 17;

  const uint4* qp = (const uint4*)(Qh + ((size_t)((b << 14) + y * WB + x)) * DIM + h * 32);
  uint4 q0 = qp[0], q1 = qp[1], q2 = qp[2], q3 = qp[3];
  const unsigned qa[16] = {q0.x,q0.y,q0.z,q0.w, q1.x,q1.y,q1.z,q1.w,
                           q2.x,q2.y,q2.z,q2.w, q3.x,q3.y,q3.z,q3.w};

  const int ilo = max(0, (y - 1) >> 1), ihi = min(HT - 1, (y + 1) >> 1);
  const int jlo = max(0, (x - 1) >> 1), jhi = min(WT - 1, (x + 1) >> 1);

  float s = 0.f;
  for (int i = ilo; i <= ihi; ++i)
    for (int j = jlo; j <= jhi; ++j) {
      const int w = i * WT + j;
      const int p = (y + 1 - 2 * i) * 4 + (x + 1 - 2 * j);
      const uint4* kp = (const uint4*)(KVh + ((size_t)((b << 12) + w)) * KVD + h * 32);
      uint4 k0 = kp[0], k1 = kp[1], k2 = kp[2], k3 = kp[3];
      const unsigned ka[16] = {k0.x,k0.y,k0.z,k0.w, k1.x,k1.y,k1.z,k1.w,
                               k2.x,k2.y,k2.z,k2.w, k3.x,k3.y,k3.z,k3.w};
      float acc = 0.f;
#pragma unroll
      for (int q = 0; q < 16; ++q) {
        acc = fmaf(__uint_as_float(qa[q] << 16),
                   __uint_as_float(ka[q] << 16), acc);
        acc = fmaf(__uint_as_float(qa[q] & 0xffff0000u),
                   __uint_as_float(ka[q] & 0xffff0000u), acc);
      }
      const float e = expf(acc * SCALE + rel_init[p] + rel_bias[p]);
      E[((size_t)((b << 12) + w)) * 128 + h * NP2 + p] = e;
      s += e;
    }
  S[(size_t)((b * HEADS + h) << 14) + y * WB + x] = s;
}

// ---------------------------------------------------------------------------
// out_pre[b,pix,c] (bf16) = sum over covering windows of (E/S_scrambled) * v.
// R computed inline (faithful to reference reshape quirk:
// h_eff = w>>9; w_eff = (w&511)*8 + h; padding divisor -> 1).
// 8 channels/thread, 32 threads/pixel, 8 pixels/block.
// ---------------------------------------------------------------------------
__global__ __launch_bounds__(256) void o_kernel(
    const float* __restrict__ E, const float* __restrict__ S,
    const unsigned short* __restrict__ KVh,
    unsigned short* __restrict__ out_pre)
{
  const int t  = threadIdx.x;
  const int pg = blockIdx.x * 8 + (t >> 5);
  const int b  = pg >> 14;
  const int yx = pg & 16383;
  const int y  = yx >> 7, x = yx & 127;
  const int c8 = t & 31;
  const int h  = c8 >> 2;

  const int ilo = max(0, (y - 1) >> 1), ihi = min(HT - 1, (y + 1) >> 1);
  const int jlo = max(0, (x - 1) >> 1), jhi = min(WT - 1, (x + 1) >> 1);

  float acc[8] = {};
  for (int i = ilo; i <= ihi; ++i)
    for (int j = jlo; j <= jhi; ++j) {
      const int w = i * WT + j;
      const int p = (y + 1 - 2 * i) * 4 + (x + 1 - 2 * j);
      // inline R = E / S_scrambled
      const float e = E[((size_t)((b << 12) + w)) * 128 + h * NP2 + p];
      const int h_eff = w >> 9;
      const int w_eff = ((w & 511) << 3) + h;
      const int i2 = w_eff >> 6, j2 = w_eff & 63;
      const int y2 = 2 * i2 + (p >> 2) - 1;
      const int x2 = 2 * j2 + (p & 3) - 1;
      float sd = 1.f;
      if ((unsigned)y2 < (unsigned)HB && (unsigned)x2 < (unsigned)WB)
        sd = S[(size_t)((b * HEADS + h_eff) * NPIX) + y2 * WB + x2];
      const float rr = e / sd;

      const uint4 v = *(const uint4*)(KVh + ((size_t)(b * NWIN + w)) * KVD + 256 + c8 * 8);
      const unsigned vv[4] = {v.x, v.y, v.z, v.w};
#pragma unroll
      for (int q = 0; q < 4; ++q) {
        acc[2*q]   = fmaf(rr, __uint_as_float(vv[q] << 16),         acc[2*q]);
        acc[2*q+1] = fmaf(rr, __uint_as_float(vv[q] & 0xffff0000u), acc[2*q+1]);
      }
    }

  uint4 ov;
  ov.x = (unsigned)f2bf(acc[0]) | ((unsigned)f2bf(acc[1]) << 16);
  ov.y = (unsigned)f2bf(acc[2]) | ((unsigned)f2bf(acc[3]) << 16);
  ov.z = (unsigned)f2bf(acc[4]) | ((unsigned)f2bf(acc[5]) << 16);
  ov.w = (unsigned)f2bf(acc[6]) | ((unsigned)f2bf(acc[7]) << 16);
  *(uint4*)(out_pre + (size_t)pg * DIM + c8 * 8) = ov;
}

// ---------------------------------------------------------------------------
extern "C" void kernel_launch(void* const* d_in, const int* in_sizes, int n_in,
                              void* d_out, int out_size, void* d_ws, size_t ws_size,
                              hipStream_t stream) {
  const float* Xt       = (const float*)d_in[0];
  const float* Xb       = (const float*)d_in[1];
  const float* q_w      = (const float*)d_in[2];
  const float* kv_w     = (const float*)d_in[3];
  const float* proj_w   = (const float*)d_in[4];
  const float* proj_b   = (const float*)d_in[5];
  const float* rel_init = (const float*)d_in[6];
  const float* rel_bias = (const float*)d_in[7];
  float* out = (float*)d_out;

  char* ws = (char*)d_ws;
  const size_t nXb = (size_t)B_ * NPIX * DIM;
  const size_t nXt = (size_t)B_ * NWIN * KVD;
  const size_t nQW = (size_t)DIM * DIM;
  const size_t nKVW = (size_t)KVD * KVD;
  unsigned short* Qh   = (unsigned short*)ws;  ws += nXb * 2;   // 32 MB (reused as Oh)
  unsigned short* Xth  = (unsigned short*)ws;  ws += nXt * 2;   // 16 MB
  unsigned short* KVh  = (unsigned short*)ws;  ws += nXt * 2;   // 16 MB
  float*          E    = (float*)ws;           ws += (size_t)B_ * NWIN * 128 * 4;   // 8 MB
  float*          S    = (float*)ws;           ws += (size_t)B_ * HEADS * NPIX * 4; // 2 MB
  unsigned short* qwh  = (unsigned short*)ws;  ws += nQW * 2;
  unsigned short* kvwh = (unsigned short*)ws;  ws += nKVW * 2;
  unsigned short* pwh  = (unsigned short*)ws;  ws += nQW * 2;
  unsigned short* Oh   = Qh;            // alias: Qh dead after es_kernel

  const dim3 blk(256);

  // 0) merged cast: Xt + all three weights -> bf16
  cast_all<<<dim3(NCAST4 / 256), blk, 0, stream>>>(
      Xt, q_w, kv_w, proj_w, Xth, qwh, kvwh, pwh);

  // 1+2) merged Q proj (fp32 A, pipelined) + KV proj
  g12_kernel<<<dim3(1024), blk, 0, stream>>>(Xb, qwh, Qh, Xth, kvwh, KVh);

  // 3) fused E + S
  es_kernel<<<dim3(B_ * NPIX * HEADS / 256), blk, 0, stream>>>(
      Qh, KVh, rel_init, rel_bias, E, S);

  // 4+5) Oh = fold((E/S) * v)   [bf16, into Qh buffer; r fused]
  o_kernel<<<dim3(B_ * NPIX / 8), blk, 0, stream>>>(E, S, KVh, Oh);

  // 6) out = Oh @ proj_w^T + proj_b
  g3_kernel<<<dim3(B_ * NPIX / 64), blk, 0, stream>>>(Oh, pwh, proj_b, out);
}

// Round 6
// 254.454 us; speedup vs baseline: 1.2312x; 1.0121x over previous
//
#include <hip/hip_runtime.h>
#include <math.h>

// ---------------------------------------------------------------------------
// InterLevelAttention, MI355X. Fixed shapes from setup_inputs().
// Round 11: best measured combination. R0 baseline structure (simple g3,
// separate r_kernel) + R1's counted-vmcnt pipelined g12 (proven 56.5us).
// Persistent-B (>64KB static LDS) shelved: two container failures.
// ---------------------------------------------------------------------------
constexpr int B_    = 4;
constexpr int HT    = 64,  WT = 64;
constexpr int HB    = 128, WB = 128;
constexpr int DIM   = 256;
constexpr int KVD   = 512;
constexpr int HEADS = 8;
constexpr int NP2   = 16;
constexpr int NPIX  = HB * WB;       // 16384
constexpr int NWIN  = HT * WT;       // 4096
constexpr float SCALE = 0.17677669529663687f;  // 32^-0.5

using bf16x8 = __attribute__((ext_vector_type(8))) short;
using f32x4  = __attribute__((ext_vector_type(4))) float;

__device__ __forceinline__ unsigned short f2bf(float f) {
  union { float f; unsigned u; } v; v.f = f;
  unsigned r = v.u + 0x7fffu + ((v.u >> 16) & 1u);   // RNE
  return (unsigned short)(r >> 16);
}
// pack 2 fp32 -> 2 bf16 in one dword: round-half-away (+0x8000) + v_perm.
__device__ __forceinline__ unsigned pack_bf16(float x, float y) {
  unsigned ux = __float_as_uint(x) + 0x8000u;
  unsigned uy = __float_as_uint(y) + 0x8000u;
  return __builtin_amdgcn_perm(uy, ux, 0x07060302u);  // lo=hi16(ux), hi=hi16(uy)
}

__device__ __forceinline__ void wait_vm0() { asm volatile("s_waitcnt vmcnt(0)" ::: "memory"); }
__device__ __forceinline__ void wait_vm4() { asm volatile("s_waitcnt vmcnt(4)" ::: "memory"); }
__device__ __forceinline__ void wait_vm6() { asm volatile("s_waitcnt vmcnt(6)" ::: "memory"); }
__device__ __forceinline__ void wait_lgkm0() { asm volatile("s_waitcnt lgkmcnt(0)" ::: "memory"); }

__device__ __forceinline__ void gll16(const void* g, void* l) {
  __builtin_amdgcn_global_load_lds(
      (const __attribute__((address_space(1))) unsigned int*)g,
      (__attribute__((address_space(3))) unsigned int*)l, 16, 0, 0);
}

// ---------------------------------------------------------------------------
// Merged fp32->bf16 cast: Xt + q_w + kv_w + proj_w in one launch.
// ---------------------------------------------------------------------------
constexpr int NXT4  = B_ * NWIN * KVD / 4;   // 2,097,152
constexpr int NQW4  = DIM * DIM / 4;         // 16,384
constexpr int NKVW4 = KVD * KVD / 4;         // 65,536
constexpr int NCAST4 = NXT4 + NQW4 + NKVW4 + NQW4;

__global__ __launch_bounds__(256) void cast_all(
    const float* __restrict__ Xt, const float* __restrict__ qw,
    const float* __restrict__ kvw, const float* __restrict__ pw,
    unsigned short* __restrict__ Xth, unsigned short* __restrict__ qwh,
    unsigned short* __restrict__ kvwh, unsigned short* __restrict__ pwh)
{
  const int i = blockIdx.x * 256 + threadIdx.x;
  const float* src; unsigned short* dst; int off;
  if (i < NXT4)                     { src = Xt;  dst = Xth;  off = i; }
  else if (i < NXT4 + NQW4)         { src = qw;  dst = qwh;  off = i - NXT4; }
  else if (i < NXT4 + NQW4 + NKVW4) { src = kvw; dst = kvwh; off = i - NXT4 - NQW4; }
  else                              { src = pw;  dst = pwh;  off = i - NXT4 - NQW4 - NKVW4; }
  float4 v = ((const float4*)src)[off];
  ushort4 o;
  o.x = f2bf(v.x); o.y = f2bf(v.y); o.z = f2bf(v.z); o.w = f2bf(v.w);
  ((ushort4*)dst)[off] = o;
}

// ---------------------------------------------------------------------------
// Pipelined MFMA GEMM core (R1, proven): C[M,N] = A[M,K] @ Bw[N,K]^T.
// BM=128, BK=32, BN in {128,256}. 256 thr = 4 waves (2x2).
// Next K-tile staged at top of iter, drained with counted vmcnt at the
// bottom (raw s_barrier — no compiler vmcnt(0) drain).
// ---------------------------------------------------------------------------
template<bool AF32, int BN, bool BF16_OUT, bool BIAS>
__device__ __forceinline__ void gemm_core(
    const void* __restrict__ Ap, const unsigned short* __restrict__ Bw,
    const float* __restrict__ bias, void* __restrict__ Cp,
    int M, int N, int K, int bx, int by,
    unsigned short* Ash, unsigned short* Bsh)
{
  constexpr int NT = BN / 32;          // n-frags per wave
  constexpr int NB = BN / 64;          // B global_load_lds per thread per tile
  const int tid  = threadIdx.x;
  const int wave = tid >> 6;
  const int lane = tid & 63;
  const int m0 = bx * 128;
  const int n0 = by * BN;
  const int wm = (wave >> 1) * 64;
  const int wn = (wave & 1) * (BN / 2);

  f32x4 acc[4][NT];
#pragma unroll
  for (int i = 0; i < 4; ++i)
#pragma unroll
    for (int j = 0; j < NT; ++j) { f32x4 z = {0.f, 0.f, 0.f, 0.f}; acc[i][j] = z; }

  const int fr = lane & 15;
  const int fk = (lane >> 4) * 8;
  const int niter = K >> 5;

  auto stageB = [&](int kk, int buf) {
#pragma unroll
    for (int i = 0; i < NB; ++i) {
      const int c = i * 256 + wave * 64 + lane, row = c >> 2, ko = (c & 3) * 8;
      gll16(Bw + (size_t)(n0 + row) * K + kk + ko,
            (char*)Bsh + buf * (BN * 64) + i * 4096 + wave * 1024);
    }
  };

  auto compute = [&](int bufA, int bufB) {
    bf16x8 af[4], bfr[NT];
    const unsigned short* Abase = Ash + bufA * 4096;
    const unsigned short* Bbase = Bsh + bufB * (BN * 32);
#pragma unroll
    for (int x = 0; x < 4; ++x)
      af[x] = *(const bf16x8*)&Abase[(wm + x * 16 + fr) * 32 + fk];
#pragma unroll
    for (int x = 0; x < NT; ++x)
      bfr[x] = *(const bf16x8*)&Bbase[(wn + x * 16 + fr) * 32 + fk];
#pragma unroll
    for (int mt = 0; mt < 4; ++mt)
#pragma unroll
      for (int nt = 0; nt < NT; ++nt)
        acc[mt][nt] = __builtin_amdgcn_mfma_f32_16x16x32_bf16(
            af[mt], bfr[nt], acc[mt][nt], 0, 0, 0);
  };

  if constexpr (AF32) {
    // G1: A fp32 -> reg prefetch -> pack -> ds_write. 2-buf A and B.
    const float* Af = (const float*)Ap;
    float4 areg[4];
    auto loadA = [&](int kk) {
#pragma unroll
      for (int u = 0; u < 4; ++u) {
        const int c = u * 256 + tid, row = c >> 3, kq = (c & 7) * 4;
        areg[u] = *(const float4*)(Af + (size_t)(m0 + row) * K + kk + kq);
      }
    };
    auto writeA = [&](int buf) {
#pragma unroll
      for (int u = 0; u < 4; ++u) {
        const int c = u * 256 + tid, row = c >> 3, kq = (c & 7) * 4;
        uint2 pk;
        pk.x = pack_bf16(areg[u].x, areg[u].y);
        pk.y = pack_bf16(areg[u].z, areg[u].w);
        *(uint2*)&Ash[buf * 4096 + row * 32 + kq] = pk;
      }
    };

    // prologue: tile0 staged, areg(1) in flight
    loadA(0);
    stageB(0, 0);
    writeA(0);          // compiler drains areg(0) here
    loadA(32);          // areg(1)
    wait_vm4();         // drain B(0); leave areg(1) in flight
    wait_lgkm0();
    __builtin_amdgcn_s_barrier();

    for (int t = 0; t < niter; ++t) {
      const int cur = t & 1;
      const int kk = t << 5;
      if (t + 1 < niter) stageB(kk + 32, cur ^ 1);   // B(t+1) flies under MFMAs
      compute(cur, cur);
      if (t + 1 < niter) {
        writeA(cur ^ 1);              // areg(t+1): had a full iteration of flight
        if (t + 2 < niter) {
          loadA(kk + 64);             // areg(t+2)
          wait_vm4();                 // drain B(t+1); leave areg(t+2)
        } else {
          wait_vm0();
        }
        wait_lgkm0();                 // ds_write visible before barrier
        __builtin_amdgcn_s_barrier();
      }
    }
  } else {
    // G2: A bf16 via global_load_lds. Depth-2 prefetch, 3-buf LDS.
    auto stageA = [&](int kk, int buf) {
      const unsigned short* Ab = (const unsigned short*)Ap;
#pragma unroll
      for (int i = 0; i < 2; ++i) {
        const int c = i * 256 + wave * 64 + lane, row = c >> 2, ko = (c & 3) * 8;
        gll16(Ab + (size_t)(m0 + row) * K + kk + ko,
              (char*)Ash + buf * 8192 + i * 4096 + wave * 1024);
      }
    };
    auto wait_batch = [&]() {      // leave one tile-batch (2+NB loads) in flight
      if constexpr (NB == 2) wait_vm4(); else wait_vm6();
    };

    // prologue: stage tiles 0 and 1; drain batch0 only
    stageA(0, 0);  stageB(0, 0);
    stageA(32, 1); stageB(32, 1);
    wait_batch();
    __builtin_amdgcn_s_barrier();

    int rd = 0, wr = 2;
    for (int t = 0; t < niter; ++t) {
      const int kk = t << 5;
      if (t + 2 < niter) { stageA(kk + 64, wr); stageB(kk + 64, wr); }
      compute(rd, rd);
      if (t + 1 < niter) {
        if (t + 2 < niter) wait_batch();   // drain batch(t+1); leave batch(t+2)
        else               wait_vm0();
        __builtin_amdgcn_s_barrier();
      }
      rd = (rd == 2) ? 0 : rd + 1;
      wr = (wr == 2) ? 0 : wr + 1;
    }
  }

  // epilogue: C/D layout col=lane&15, row=(lane>>4)*4+reg
  const int col0 = lane & 15;
  const int rb   = (lane >> 4) * 4;
#pragma unroll
  for (int mt = 0; mt < 4; ++mt)
#pragma unroll
    for (int nt = 0; nt < NT; ++nt) {
      const int col = n0 + wn + nt * 16 + col0;
      float bv = BIAS ? bias[col] : 0.f;
#pragma unroll
      for (int r = 0; r < 4; ++r) {
        const int row = m0 + wm + mt * 16 + rb + r;
        const float v = acc[mt][nt][r] + bv;
        if (BF16_OUT) ((unsigned short*)Cp)[(size_t)row * N + col] = f2bf(v);
        else          ((float*)Cp)[(size_t)row * N + col] = v;
      }
    }
}

// ---------------------------------------------------------------------------
// Simple (R0) bf16-A GEMM core for g3: sync / stage A+B / sync / compute.
// ---------------------------------------------------------------------------
template<int BN, bool BF16_OUT, bool BIAS>
__device__ __forceinline__ void gemm_simple(
    const unsigned short* __restrict__ Ab, const unsigned short* __restrict__ Bw,
    const float* __restrict__ bias, void* __restrict__ Cp,
    int M, int N, int K, int bx, int by,
    unsigned short* Ash, unsigned short* Bsh)
{
  constexpr int NT = BN / 32;
  constexpr int NB = BN / 64;
  const int tid  = threadIdx.x;
  const int wave = tid >> 6;
  const int lane = tid & 63;
  const int m0 = bx * 128;
  const int n0 = by * BN;
  const int wm = (wave >> 1) * 64;
  const int wn = (wave & 1) * (BN / 2);

  f32x4 acc[4][NT];
#pragma unroll
  for (int i = 0; i < 4; ++i)
#pragma unroll
    for (int j = 0; j < NT; ++j) { f32x4 z = {0.f, 0.f, 0.f, 0.f}; acc[i][j] = z; }

  const int fr = lane & 15;
  const int fk = (lane >> 4) * 8;

  for (int kk = 0; kk < K; kk += 32) {
    __syncthreads();                    // previous iter done reading LDS
#pragma unroll
    for (int i = 0; i < 2; ++i) {
      const int c = i * 256 + wave * 64 + lane, row = c >> 2, ko = (c & 3) * 8;
      gll16(Ab + (size_t)(m0 + row) * K + kk + ko,
            (char*)Ash + i * 4096 + wave * 1024);
    }
#pragma unroll
    for (int i = 0; i < NB; ++i) {
      const int c = i * 256 + wave * 64 + lane, row = c >> 2, ko = (c & 3) * 8;
      gll16(Bw + (size_t)(n0 + row) * K + kk + ko,
            (char*)Bsh + i * 4096 + wave * 1024);
    }
    __syncthreads();                    // staging visible

    bf16x8 af[4], bf[NT];
#pragma unroll
    for (int t = 0; t < 4; ++t)
      af[t] = *(const bf16x8*)&Ash[(wm + t * 16 + fr) * 32 + fk];
#pragma unroll
    for (int t = 0; t < NT; ++t)
      bf[t] = *(const bf16x8*)&Bsh[(wn + t * 16 + fr) * 32 + fk];
#pragma unroll
    for (int mt = 0; mt < 4; ++mt)
#pragma unroll
      for (int nt = 0; nt < NT; ++nt)
        acc[mt][nt] = __builtin_amdgcn_mfma_f32_16x16x32_bf16(
            af[mt], bf[nt], acc[mt][nt], 0, 0, 0);
  }

  const int col0 = lane & 15;
  const int rb   = (lane >> 4) * 4;
#pragma unroll
  for (int mt = 0; mt < 4; ++mt)
#pragma unroll
    for (int nt = 0; nt < NT; ++nt) {
      const int col = n0 + wn + nt * 16 + col0;
      float bv = BIAS ? bias[col] : 0.f;
#pragma unroll
      for (int r = 0; r < 4; ++r) {
        const int row = m0 + wm + mt * 16 + rb + r;
        const float v = acc[mt][nt][r] + bv;
        if (BF16_OUT) ((unsigned short*)Cp)[(size_t)row * N + col] = f2bf(v);
        else          ((float*)Cp)[(size_t)row * N + col] = v;
      }
    }
}

// ---------------------------------------------------------------------------
// Merged GEMM1 (Q proj, fp32 A, 128x256) + GEMM2 (KV proj, bf16, 128x128).
// Even block ids -> G1 (512), odd -> G2 (512): each CU hosts both kinds.
// LDS: Ash 3-buf (24 KB), Bsh max(2x16 KB [G1], 3x8 KB [G2]) = 32 KB.
// ---------------------------------------------------------------------------
__global__ __launch_bounds__(256, 2) void g12_kernel(
    const float* __restrict__ Xb, const unsigned short* __restrict__ qwh,
    unsigned short* __restrict__ Qh,
    const unsigned short* __restrict__ Xth, const unsigned short* __restrict__ kvwh,
    unsigned short* __restrict__ KVh)
{
  __shared__ unsigned short Ash[3 * 128 * 32];   // 24 KB
  __shared__ unsigned short Bsh[2 * 256 * 32];   // 32 KB
  const int id = blockIdx.x;
  if ((id & 1) == 0) {
    gemm_core<true, 256, true, false>(Xb, qwh, nullptr, Qh,
        B_ * NPIX, DIM, DIM, id >> 1, 0, Ash, Bsh);
  } else {
    const int t = id >> 1;
    gemm_core<false, 128, true, false>(Xth, kvwh, nullptr, KVh,
        B_ * NWIN, KVD, KVD, t >> 2, t & 3, Ash, Bsh);
  }
}

// GEMM3 (R0 config): out proj, bf16 A, 128x256, fp32 out + bias. 512 blocks.
__global__ __launch_bounds__(256, 2) void g3_kernel(
    const unsigned short* __restrict__ Oh, const unsigned short* __restrict__ pwh,
    const float* __restrict__ pb, float* __restrict__ out)
{
  __shared__ unsigned short Ash[128 * 32];   // 8 KB
  __shared__ unsigned short Bsh[256 * 32];   // 16 KB
  gemm_simple<256, false, true>(Oh, pwh, pb, out,
      B_ * NPIX, DIM, DIM, blockIdx.x, 0, Ash, Bsh);
}

// ---------------------------------------------------------------------------
// Fused e+s: one thread per (b, pixel, h). q loaded once; E contributions for
// the <=4 covering windows + folded sum S emitted directly.
// ---------------------------------------------------------------------------
__global__ __launch_bounds__(256) void es_kernel(
    const unsigned short* __restrict__ Qh, const unsigned short* __restrict__ KVh,
    const float* __restrict__ rel_init, const float* __restrict__ rel_bias,
    float* __restrict__ E, float* __restrict__ S)
{
  const int idx = blockIdx.x * 256 + threadIdx.x;
  const int h = idx & 7;
  const int x = (idx >> 3) & 127;
  const int y = (idx >> 10) & 127;
  const int b = idx >> 17;

  const uint4* qp = (const uint4*)(Qh + ((size_t)((b << 14) + y * WB + x)) * DIM + h * 32);
  uint4 q0 = qp[0], q1 = qp[1], q2 = qp[2], q3 = qp[3];
  const unsigned qa[16] = {q0.x,q0.y,q0.z,q0.w, q1.x,q1.y,q1.z,q1.w,
                           q2.x,q2.y,q2.z,q2.w, q3.x,q3.y,q3.z,q3.w};

  const int ilo = max(0, (y - 1) >> 1), ihi = min(HT - 1, (y + 1) >> 1);
  const int jlo = max(0, (x - 1) >> 1), jhi = min(WT - 1, (x + 1) >> 1);

  float s = 0.f;
  for (int i = ilo; i <= ihi; ++i)
    for (int j = jlo; j <= jhi; ++j) {
      const int w = i * WT + j;
      const int p = (y + 1 - 2 * i) * 4 + (x + 1 - 2 * j);
      const uint4* kp = (const uint4*)(KVh + ((size_t)((b << 12) + w)) * KVD + h * 32);
      uint4 k0 = kp[0], k1 = kp[1], k2 = kp[2], k3 = kp[3];
      const unsigned ka[16] = {k0.x,k0.y,k0.z,k0.w, k1.x,k1.y,k1.z,k1.w,
                               k2.x,k2.y,k2.z,k2.w, k3.x,k3.y,k3.z,k3.w};
      float acc = 0.f;
#pragma unroll
      for (int q = 0; q < 16; ++q) {
        acc = fmaf(__uint_as_float(qa[q] << 16),
                   __uint_as_float(ka[q] << 16), acc);
        acc = fmaf(__uint_as_float(qa[q] & 0xffff0000u),
                   __uint_as_float(ka[q] & 0xffff0000u), acc);
      }
      const float e = expf(acc * SCALE + rel_init[p] + rel_bias[p]);
      E[((size_t)((b << 12) + w)) * 128 + h * NP2 + p] = e;
      s += e;
    }
  S[(size_t)((b * HEADS + h) << 14) + y * WB + x] = s;
}

// ---------------------------------------------------------------------------
// R[b,w,h,p] = E / S_scrambled (faithful to reference reshape quirk):
// h_eff = w>>9; w_eff = (w&511)*8 + h; p_eff = p; padding divisor -> 1.
// ---------------------------------------------------------------------------
__global__ __launch_bounds__(256) void r_kernel(
    const float* __restrict__ E, const float* __restrict__ S,
    float* __restrict__ R)
{
  const int idx = blockIdx.x * 256 + threadIdx.x;
  const int b  = idx >> 19;
  const int r  = idx & 524287;
  const int w  = r >> 7;
  const int t7 = r & 127;
  const int h  = t7 >> 4, p = t7 & 15;

  const int h_eff = w >> 9;
  const int w_eff = ((w & 511) << 3) + h;
  const int i2 = w_eff >> 6, j2 = w_eff & 63;
  const int y2 = 2 * i2 + (p >> 2) - 1;
  const int x2 = 2 * j2 + (p & 3) - 1;
  float s = 1.f;
  if ((unsigned)y2 < (unsigned)HB && (unsigned)x2 < (unsigned)WB)
    s = S[(size_t)((b * HEADS + h_eff) * NPIX) + y2 * WB + x2];
  R[idx] = E[idx] / s;
}

// ---------------------------------------------------------------------------
// out_pre[b,pix,c] (bf16) = sum over covering windows of R * v.
// 8 channels/thread, 32 threads/pixel, 8 pixels/block.
// ---------------------------------------------------------------------------
__global__ __launch_bounds__(256) void o_kernel(
    const float* __restrict__ R, const unsigned short* __restrict__ KVh,
    unsigned short* __restrict__ out_pre)
{
  const int t  = threadIdx.x;
  const int pg = blockIdx.x * 8 + (t >> 5);
  const int b  = pg >> 14;
  const int yx = pg & 16383;
  const int y  = yx >> 7, x = yx & 127;
  const int c8 = t & 31;
  const int h  = c8 >> 2;

  const int ilo = max(0, (y - 1) >> 1), ihi = min(HT - 1, (y + 1) >> 1);
  const int jlo = max(0, (x - 1) >> 1), jhi = min(WT - 1, (x + 1) >> 1);

  float acc[8] = {};
  for (int i = ilo; i <= ihi; ++i)
    for (int j = jlo; j <= jhi; ++j) {
      const int w = i * WT + j;
      const int p = (y + 1 - 2 * i) * 4 + (x + 1 - 2 * j);
      const float rr = R[((size_t)(b * NWIN + w)) * 128 + h * NP2 + p];
      const uint4 v = *(const uint4*)(KVh + ((size_t)(b * NWIN + w)) * KVD + 256 + c8 * 8);
      const unsigned vv[4] = {v.x, v.y, v.z, v.w};
#pragma unroll
      for (int q = 0; q < 4; ++q) {
        acc[2*q]   = fmaf(rr, __uint_as_float(vv[q] << 16),         acc[2*q]);
        acc[2*q+1] = fmaf(rr, __uint_as_float(vv[q] & 0xffff0000u), acc[2*q+1]);
      }
    }

  uint4 ov;
  ov.x = (unsigned)f2bf(acc[0]) | ((unsigned)f2bf(acc[1]) << 16);
  ov.y = (unsigned)f2bf(acc[2]) | ((unsigned)f2bf(acc[3]) << 16);
  ov.z = (unsigned)f2bf(acc[4]) | ((unsigned)f2bf(acc[5]) << 16);
  ov.w = (unsigned)f2bf(acc[6]) | ((unsigned)f2bf(acc[7]) << 16);
  *(uint4*)(out_pre + (size_t)pg * DIM + c8 * 8) = ov;
}

// ---------------------------------------------------------------------------
extern "C" void kernel_launch(void* const* d_in, const int* in_sizes, int n_in,
                              void* d_out, int out_size, void* d_ws, size_t ws_size,
                              hipStream_t stream) {
  const float* Xt       = (const float*)d_in[0];
  const float* Xb       = (const float*)d_in[1];
  const float* q_w      = (const float*)d_in[2];
  const float* kv_w     = (const float*)d_in[3];
  const float* proj_w   = (const float*)d_in[4];
  const float* proj_b   = (const float*)d_in[5];
  const float* rel_init = (const float*)d_in[6];
  const float* rel_bias = (const float*)d_in[7];
  float* out = (float*)d_out;

  char* ws = (char*)d_ws;
  const size_t nXb = (size_t)B_ * NPIX * DIM;
  const size_t nXt = (size_t)B_ * NWIN * KVD;
  const size_t nQW = (size_t)DIM * DIM;
  const size_t nKVW = (size_t)KVD * KVD;
  unsigned short* Qh   = (unsigned short*)ws;  ws += nXb * 2;   // 32 MB (reused as Oh)
  unsigned short* Xth  = (unsigned short*)ws;  ws += nXt * 2;   // 16 MB (reused as R)
  unsigned short* KVh  = (unsigned short*)ws;  ws += nXt * 2;   // 16 MB
  float*          E    = (float*)ws;           ws += (size_t)B_ * NWIN * 128 * 4;   // 8 MB
  float*          S    = (float*)ws;           ws += (size_t)B_ * HEADS * NPIX * 4; // 2 MB
  unsigned short* qwh  = (unsigned short*)ws;  ws += nQW * 2;
  unsigned short* kvwh = (unsigned short*)ws;  ws += nKVW * 2;
  unsigned short* pwh  = (unsigned short*)ws;  ws += nQW * 2;
  float*          R    = (float*)Xth;   // alias: Xth dead after g12
  unsigned short* Oh   = Qh;            // alias: Qh dead after es_kernel

  const dim3 blk(256);

  // 0) merged cast: Xt + all three weights -> bf16
  cast_all<<<dim3(NCAST4 / 256), blk, 0, stream>>>(
      Xt, q_w, kv_w, proj_w, Xth, qwh, kvwh, pwh);

  // 1+2) merged Q proj (fp32 A, pipelined) + KV proj
  g12_kernel<<<dim3(1024), blk, 0, stream>>>(Xb, qwh, Qh, Xth, kvwh, KVh);

  // 3) fused E + S
  es_kernel<<<dim3(B_ * NPIX * HEADS / 256), blk, 0, stream>>>(
      Qh, KVh, rel_init, rel_bias, E, S);

  // 4) R = E / S_scrambled   [into Xth buffer]
  r_kernel<<<dim3(B_ * NWIN * 128 / 256), blk, 0, stream>>>(E, S, R);

  // 5) Oh = fold(R * v)      [bf16, into Qh buffer]
  o_kernel<<<dim3(B_ * NPIX / 8), blk, 0, stream>>>(R, KVh, Oh);

  // 6) out = Oh @ proj_w^T + proj_b
  g3_kernel<<<dim3(B_ * NPIX / 128), blk, 0, stream>>>(Oh, pwh, proj_b, out);
}